// Round 1
// baseline (8782.310 us; speedup 1.0000x reference)
//
#include <hip/hip_runtime.h>

typedef float f32x4 __attribute__((ext_vector_type(4)));
typedef __bf16 bf16x8 __attribute__((ext_vector_type(8)));

#define DI static __device__ __forceinline__

DI unsigned short f2bf(float f) {
  unsigned u = __float_as_uint(f);
  u = (u + 0x7fffu + ((u >> 16) & 1u)) >> 16;
  return (unsigned short)u;
}
DI float sigm(float x) { return 1.0f / (1.0f + expf(-x)); }
DI float dot4(f32x4 a, f32x4 b) { return a[0]*b[0] + a[1]*b[1] + a[2]*b[2] + a[3]*b[3]; }
DI float rsum32(float v) {
  v += __shfl_xor(v, 1); v += __shfl_xor(v, 2); v += __shfl_xor(v, 4);
  v += __shfl_xor(v, 8); v += __shfl_xor(v, 16);
  return v;
}

// ---------------------------------------------------------------------------
// Fold the tiny per-feature projections + fi into M[1024][16], b0[1024]:
// proj[bs,h] = tanh( sum_f M[h,f]*feat[bs,f] + b0[h] )
// ---------------------------------------------------------------------------
__global__ void k_fold(const float* __restrict__ tW, const float* __restrict__ tb,
                       const float* __restrict__ hW, const float* __restrict__ hb,
                       const float* __restrict__ cW, const float* __restrict__ cb,
                       const float* __restrict__ tiW, const float* __restrict__ tib,
                       const float* __restrict__ oW, const float* __restrict__ ob,
                       const float* __restrict__ fiW, const float* __restrict__ fib,
                       float* __restrict__ M, float* __restrict__ b0v)
{
  int g = blockIdx.x * 256 + threadIdx.x;
  if (g >= 1024 * 17) return;
  int h = g / 17, f = g - h * 17;
  const float* fw = fiW + (size_t)h * 2048;
  float s = 0.f;
  if (f == 16) {
    for (int k = 0; k < 256; ++k) s += fw[k] * tb[k];
    for (int k = 0; k < 256; ++k) s += fw[256 + k] * hb[k];
    for (int k = 0; k < 256; ++k) s += fw[512 + k] * cb[k];
    for (int k = 0; k < 256; ++k) s += fw[768 + k] * tib[k];
    for (int r = 0; r < 1024; ++r) s += fw[1024 + r] * ob[r];
    b0v[h] = s + fib[h];
  } else if (f == 0) {
    for (int k = 0; k < 256; ++k) s += fw[k] * tW[k];
    M[h * 16 + 0] = s;
  } else if (f == 1) {
    for (int k = 0; k < 256; ++k) s += fw[256 + k] * hW[k];
    M[h * 16 + 1] = s;
  } else if (f == 2) {
    for (int k = 0; k < 256; ++k) s += fw[512 + k] * cW[k];
    M[h * 16 + 2] = s;
  } else if (f == 11) {
    for (int k = 0; k < 256; ++k) s += fw[768 + k] * tiW[2 * k];
    M[h * 16 + 11] = s;
  } else if (f == 12) {
    for (int k = 0; k < 256; ++k) s += fw[768 + k] * tiW[2 * k + 1];
    M[h * 16 + 12] = s;
  } else {
    int col = (f <= 10) ? (f - 3) : (f - 5);
    for (int r = 0; r < 1024; ++r) s += fw[1024 + r] * oW[r * 11 + col];
    M[h * 16 + f] = s;
  }
}

__global__ __launch_bounds__(256)
void k_proj(const float* __restrict__ feat, const float* __restrict__ M,
            const float* __restrict__ b0v, float* __restrict__ proj)
{
  __shared__ float ft[16];
  int bs = blockIdx.x;
  int h = blockIdx.y * 256 + threadIdx.x;
  if (threadIdx.x < 16) ft[threadIdx.x] = feat[bs * 16 + threadIdx.x];
  __syncthreads();
  float sum = b0v[h];
  const float* mr = M + h * 16;
#pragma unroll
  for (int f = 0; f < 16; ++f) sum += mr[f] * ft[f];
  proj[(size_t)bs * 1024 + h] = tanhf(sum);
}

// ---------------------------------------------------------------------------
// fp32 -> bf16 converters
// ---------------------------------------------------------------------------
__global__ void k_tobf4(const float* __restrict__ src, unsigned short* __restrict__ dst, int n4)
{
  int i = blockIdx.x * 256 + threadIdx.x;
  if (i >= n4) return;
  f32x4 v = *(const f32x4*)(src + (size_t)i * 4);
  uint2 o;
  o.x = (unsigned)f2bf(v[0]) | ((unsigned)f2bf(v[1]) << 16);
  o.y = (unsigned)f2bf(v[2]) | ((unsigned)f2bf(v[3]) << 16);
  *(uint2*)(dst + (size_t)i * 4) = o;
}

__global__ void k_tobf_wih2(const float* __restrict__ src, unsigned short* __restrict__ dst)
{
  int r = blockIdx.x;                 // 3072
  int c = threadIdx.x * 4;            // 256*4 = 1024
  f32x4 v = *(const f32x4*)(src + (size_t)r * 2048 + 1024 + c);
  uint2 o;
  o.x = (unsigned)f2bf(v[0]) | ((unsigned)f2bf(v[1]) << 16);
  o.y = (unsigned)f2bf(v[2]) | ((unsigned)f2bf(v[3]) << 16);
  *(uint2*)(dst + (size_t)r * 1024 + c) = o;
}

// ---------------------------------------------------------------------------
// bf16 MFMA GEMM:  C[M,N] = A[M,K] * B[N,K]^T + bias[N]
// A,B fp32 in memory, converted to bf16 while staging to LDS. fp32 accum.
// MODE 0: C[r*ldc + c].  MODE 1: decoder-output remap (r = t*32+b -> out[b, t+1, c])
// Tiles 128x128x32, 256 threads = 4 waves (2x2), wave = 64x64 via 4x4 16x16x32 frags.
// ---------------------------------------------------------------------------
template<int MODE>
__global__ __launch_bounds__(256)
void gemm_bt(const float* __restrict__ A, const float* __restrict__ Bm,
             const float* __restrict__ bias, float* __restrict__ C,
             int Mm, int Nn, int K, int lda, int ldb, int ldc)
{
  __shared__ unsigned short As[128][40];
  __shared__ unsigned short Bs[128][40];
  const int tiles_m = Mm >> 7;
  const int tm = blockIdx.x % tiles_m;
  const int tn = blockIdx.x / tiles_m;
  const int tid = threadIdx.x;
  const int lane = tid & 63;
  const int wave = tid >> 6;
  const int wm = (wave & 1) * 64, wn = (wave >> 1) * 64;
  const int row = tid >> 1;
  const int kof = (tid & 1) << 4;
  const float* Ab = A + (size_t)(tm * 128 + row) * lda + kof;
  const float* Bb = Bm + (size_t)(tn * 128 + row) * ldb + kof;
  const int lr = lane & 15;
  const int lk = (lane >> 4) << 3;

  f32x4 acc[4][4];
#pragma unroll
  for (int m = 0; m < 4; ++m)
#pragma unroll
    for (int n = 0; n < 4; ++n) acc[m][n] = (f32x4){0.f, 0.f, 0.f, 0.f};

  for (int kt = 0; kt < K; kt += 32) {
    unsigned av[8], bv[8];
#pragma unroll
    for (int q = 0; q < 4; ++q) {
      f32x4 va = *(const f32x4*)(Ab + kt + q * 4);
      av[q * 2 + 0] = (unsigned)f2bf(va[0]) | ((unsigned)f2bf(va[1]) << 16);
      av[q * 2 + 1] = (unsigned)f2bf(va[2]) | ((unsigned)f2bf(va[3]) << 16);
      f32x4 vb = *(const f32x4*)(Bb + kt + q * 4);
      bv[q * 2 + 0] = (unsigned)f2bf(vb[0]) | ((unsigned)f2bf(vb[1]) << 16);
      bv[q * 2 + 1] = (unsigned)f2bf(vb[2]) | ((unsigned)f2bf(vb[3]) << 16);
    }
    __syncthreads();   // previous iteration's compute done
#pragma unroll
    for (int q = 0; q < 4; ++q) {
      uint2 ua; ua.x = av[q * 2]; ua.y = av[q * 2 + 1];
      *(uint2*)&As[row][kof + q * 4] = ua;
      uint2 ub; ub.x = bv[q * 2]; ub.y = bv[q * 2 + 1];
      *(uint2*)&Bs[row][kof + q * 4] = ub;
    }
    __syncthreads();
    bf16x8 af[4], bfv[4];
#pragma unroll
    for (int m = 0; m < 4; ++m) af[m] = *(const bf16x8*)&As[wm + m * 16 + lr][lk];
#pragma unroll
    for (int n = 0; n < 4; ++n) bfv[n] = *(const bf16x8*)&Bs[wn + n * 16 + lr][lk];
#pragma unroll
    for (int m = 0; m < 4; ++m)
#pragma unroll
      for (int n = 0; n < 4; ++n)
        acc[m][n] = __builtin_amdgcn_mfma_f32_16x16x32_bf16(af[m], bfv[n], acc[m][n], 0, 0, 0);
  }

#pragma unroll
  for (int m = 0; m < 4; ++m) {
    int r0 = tm * 128 + wm + m * 16 + ((lane >> 4) * 4);
#pragma unroll
    for (int n = 0; n < 4; ++n) {
      int c = tn * 128 + wn + n * 16 + lr;
      float bb = bias[c];
#pragma unroll
      for (int i = 0; i < 4; ++i) {
        float v = acc[m][n][i] + bb;
        int r = r0 + i;
        if (MODE == 0) {
          C[(size_t)r * ldc + c] = v;
        } else {
          if (r < 2016) {
            int t = r >> 5, b = r & 31;
            C[((size_t)b * 64 + t + 1) * 32000 + c] = v;
          }
        }
      }
    }
  }
}

// ---------------------------------------------------------------------------
// Encoder GRU step: h' from gi (precomputed) and gh = h @ whh^T (+bhh)
// grid (64 jc, 4 bg) x 256 thr. Block: 16 j's x 8 b's. Thread: 2 j x 8 b x 32 k.
// whh in bf16.  h read from enc_out[:, s-1, :] (zeros at s=0); h' -> enc_out[:, s, :].
// ---------------------------------------------------------------------------
__global__ __launch_bounds__(256)
void k_enc_step(const float* __restrict__ gi_all, const unsigned short* __restrict__ whh,
                const float* __restrict__ bhh, float* __restrict__ enc_out, int s)
{
  __shared__ float hs[8][1024];
  const int tid = threadIdx.x;
  const int jc = blockIdx.x;
  const int b0 = blockIdx.y * 8;
  const float* hprev = enc_out + (size_t)(s - 1) * 1024;   // only valid if s>0
  for (int idx = tid; idx < 2048; idx += 256) {
    int b = idx >> 8;
    int k0 = (idx & 255) << 2;
    if (s == 0) {
      *(f32x4*)&hs[b][k0] = (f32x4){0.f, 0.f, 0.f, 0.f};
    } else {
      *(f32x4*)&hs[b][k0] = *(const f32x4*)(hprev + (size_t)(b0 + b) * (128 * 1024) + k0);
    }
  }
  __syncthreads();
  const int jg = tid >> 5;          // 0..7 -> 2 j's each
  const int ks = tid & 31;          // k split
  const int j0 = jc * 16 + jg * 2;
  float acc[3][2][8];
#pragma unroll
  for (int g = 0; g < 3; ++g)
#pragma unroll
    for (int jj = 0; jj < 2; ++jj)
#pragma unroll
      for (int b = 0; b < 8; ++b) acc[g][jj][b] = 0.f;

#pragma unroll 2
  for (int i = 0; i < 8; ++i) {
    const int k = ks * 4 + i * 128;
    f32x4 hv[8];
#pragma unroll
    for (int b = 0; b < 8; ++b) hv[b] = *(const f32x4*)&hs[b][k];
#pragma unroll
    for (int jj = 0; jj < 2; ++jj) {
#pragma unroll
      for (int g = 0; g < 3; ++g) {
        const unsigned short* wr = whh + (((size_t)(g * 1024 + j0 + jj)) << 10) + k;
        uint2 wu = *(const uint2*)wr;
        f32x4 w;
        w[0] = __uint_as_float(wu.x << 16);
        w[1] = __uint_as_float(wu.x & 0xffff0000u);
        w[2] = __uint_as_float(wu.y << 16);
        w[3] = __uint_as_float(wu.y & 0xffff0000u);
#pragma unroll
        for (int b = 0; b < 8; ++b) acc[g][jj][b] += dot4(w, hv[b]);
      }
    }
  }
#pragma unroll
  for (int g = 0; g < 3; ++g)
#pragma unroll
    for (int jj = 0; jj < 2; ++jj)
#pragma unroll
      for (int b = 0; b < 8; ++b) acc[g][jj][b] = rsum32(acc[g][jj][b]);

  if (ks == 0) {
#pragma unroll
    for (int jj = 0; jj < 2; ++jj) {
      int j = j0 + jj;
      float bhr = bhh[j], bhz = bhh[1024 + j], bhn = bhh[2048 + j];
#pragma unroll
      for (int b = 0; b < 8; ++b) {
        const float* gi = gi_all + ((size_t)(b0 + b) * 128 + s) * 3072 + j;
        float r = sigm(gi[0] + acc[0][jj][b] + bhr);
        float z = sigm(gi[1024] + acc[1][jj][b] + bhz);
        float n = tanhf(gi[2048] + r * (acc[2][jj][b] + bhn));
        float hp = hs[b][j];
        enc_out[((size_t)(b0 + b) * 128 + s) * 1024 + j] = (1.f - z) * n + z * hp;
      }
    }
  }
}

// ---------------------------------------------------------------------------
// Decoder attention: one block per batch. scores = h.keys/32, softmax, ctx.
// ctx written to h2ctx[t*32+b][1024:2048].
// ---------------------------------------------------------------------------
__global__ __launch_bounds__(256)
void k_dec_attn(const float* __restrict__ h_in, int hstr,
                const float* __restrict__ keys, const float* __restrict__ enc_out,
                float* __restrict__ h2ctx, int t)
{
  __shared__ float hsh[1024];
  __shared__ float ssc[128];
  __shared__ float red[64];
  const int tid = threadIdx.x;
  const int b = blockIdx.x;
  *(f32x4*)&hsh[tid * 4] = *(const f32x4*)(h_in + (size_t)b * hstr + tid * 4);
  __syncthreads();
  if (tid < 128) {
    const float* kr = keys + ((size_t)b * 128 + tid) * 1024;
    f32x4 a = {0.f, 0.f, 0.f, 0.f};
    for (int k = 0; k < 1024; k += 4)
      a += *(const f32x4*)(kr + k) * *(const f32x4*)&hsh[k];
    ssc[tid] = (a[0] + a[1] + a[2] + a[3]) * 0.03125f;
  }
  __syncthreads();
  if (tid < 64) red[tid] = fmaxf(ssc[tid], ssc[tid + 64]);
  __syncthreads();
  if (tid < 32) red[tid] = fmaxf(red[tid], red[tid + 32]);
  __syncthreads();
  if (tid < 16) red[tid] = fmaxf(red[tid], red[tid + 16]);
  __syncthreads();
  if (tid < 8) red[tid] = fmaxf(red[tid], red[tid + 8]);
  __syncthreads();
  if (tid < 4) red[tid] = fmaxf(red[tid], red[tid + 4]);
  __syncthreads();
  if (tid < 2) red[tid] = fmaxf(red[tid], red[tid + 2]);
  __syncthreads();
  if (tid == 0) red[0] = fmaxf(red[0], red[1]);
  __syncthreads();
  float mx = red[0];
  __syncthreads();
  if (tid < 128) ssc[tid] = expf(ssc[tid] - mx);
  __syncthreads();
  if (tid < 64) red[tid] = ssc[tid] + ssc[tid + 64];
  __syncthreads();
  if (tid < 32) red[tid] = red[tid] + red[tid + 32];
  __syncthreads();
  if (tid < 16) red[tid] = red[tid] + red[tid + 16];
  __syncthreads();
  if (tid < 8) red[tid] = red[tid] + red[tid + 8];
  __syncthreads();
  if (tid < 4) red[tid] = red[tid] + red[tid + 4];
  __syncthreads();
  if (tid < 2) red[tid] = red[tid] + red[tid + 2];
  __syncthreads();
  if (tid == 0) red[0] = red[0] + red[1];
  __syncthreads();
  float inv = 1.f / red[0];
  __syncthreads();
  if (tid < 128) ssc[tid] *= inv;
  __syncthreads();
  f32x4 c4 = {0.f, 0.f, 0.f, 0.f};
  const float* eb = enc_out + (size_t)b * 128 * 1024 + tid * 4;
  for (int s2 = 0; s2 < 128; ++s2) {
    float w = ssc[s2];
    f32x4 ev = *(const f32x4*)(eb + (size_t)s2 * 1024);
    c4[0] += w * ev[0]; c4[1] += w * ev[1]; c4[2] += w * ev[2]; c4[3] += w * ev[3];
  }
  *(f32x4*)(h2ctx + ((size_t)t * 32 + b) * 2048 + 1024 + tid * 4) = c4;
}

// ---------------------------------------------------------------------------
// Decoder GRU step: gi = gi_e + ctx @ wih2^T; gh = h @ whh^T (+bhh); gates.
// grid (64 jc, 4 bg) x 256 thr. Thread: 2 j x 8 b x 32 k, two source vectors.
// h2 written to h2ctx[t*32+b][0:1024].
// ---------------------------------------------------------------------------
__global__ __launch_bounds__(256)
void k_dec_gru(const float* __restrict__ h_in, int hstr,
               const float* __restrict__ gi_e, const unsigned short* __restrict__ wih2,
               const unsigned short* __restrict__ whh, const float* __restrict__ bhh,
               float* __restrict__ h2ctx, int t)
{
  __shared__ float hs[8][1024];
  __shared__ float cs[8][1024];
  const int tid = threadIdx.x;
  const int jc = blockIdx.x;
  const int b0 = blockIdx.y * 8;
  for (int idx = tid; idx < 2048; idx += 256) {
    int b = idx >> 8;
    int k0 = (idx & 255) << 2;
    *(f32x4*)&hs[b][k0] = *(const f32x4*)(h_in + (size_t)(b0 + b) * hstr + k0);
    *(f32x4*)&cs[b][k0] = *(const f32x4*)(h2ctx + ((size_t)t * 32 + b0 + b) * 2048 + 1024 + k0);
  }
  __syncthreads();
  const int jg = tid >> 5;
  const int ks = tid & 31;
  const int j0 = jc * 16 + jg * 2;
  float arz[2][2][8], axn[2][8], ahn[2][8];
#pragma unroll
  for (int jj = 0; jj < 2; ++jj) {
#pragma unroll
    for (int b = 0; b < 8; ++b) {
      arz[0][jj][b] = 0.f; arz[1][jj][b] = 0.f; axn[jj][b] = 0.f; ahn[jj][b] = 0.f;
    }
  }
#pragma unroll 2
  for (int i = 0; i < 8; ++i) {
    const int k = ks * 4 + i * 128;
    f32x4 hv[8], cv[8];
#pragma unroll
    for (int b = 0; b < 8; ++b) { hv[b] = *(const f32x4*)&hs[b][k]; cv[b] = *(const f32x4*)&cs[b][k]; }
#pragma unroll
    for (int jj = 0; jj < 2; ++jj) {
      const size_t r0 = (size_t)(j0 + jj);
#pragma unroll
      for (int g = 0; g < 2; ++g) {
        uint2 wa = *(const uint2*)(whh + ((r0 + g * 1024) << 10) + k);
        uint2 wb = *(const uint2*)(wih2 + ((r0 + g * 1024) << 10) + k);
        f32x4 wh, wx;
        wh[0] = __uint_as_float(wa.x << 16); wh[1] = __uint_as_float(wa.x & 0xffff0000u);
        wh[2] = __uint_as_float(wa.y << 16); wh[3] = __uint_as_float(wa.y & 0xffff0000u);
        wx[0] = __uint_as_float(wb.x << 16); wx[1] = __uint_as_float(wb.x & 0xffff0000u);
        wx[2] = __uint_as_float(wb.y << 16); wx[3] = __uint_as_float(wb.y & 0xffff0000u);
#pragma unroll
        for (int b = 0; b < 8; ++b) arz[g][jj][b] += dot4(wh, hv[b]) + dot4(wx, cv[b]);
      }
      {
        uint2 wa = *(const uint2*)(whh + ((r0 + 2048) << 10) + k);
        uint2 wb = *(const uint2*)(wih2 + ((r0 + 2048) << 10) + k);
        f32x4 wh, wx;
        wh[0] = __uint_as_float(wa.x << 16); wh[1] = __uint_as_float(wa.x & 0xffff0000u);
        wh[2] = __uint_as_float(wa.y << 16); wh[3] = __uint_as_float(wa.y & 0xffff0000u);
        wx[0] = __uint_as_float(wb.x << 16); wx[1] = __uint_as_float(wb.x & 0xffff0000u);
        wx[2] = __uint_as_float(wb.y << 16); wx[3] = __uint_as_float(wb.y & 0xffff0000u);
#pragma unroll
        for (int b = 0; b < 8; ++b) {
          ahn[jj][b] += dot4(wh, hv[b]);
          axn[jj][b] += dot4(wx, cv[b]);
        }
      }
    }
  }
#pragma unroll
  for (int jj = 0; jj < 2; ++jj)
#pragma unroll
    for (int b = 0; b < 8; ++b) {
      arz[0][jj][b] = rsum32(arz[0][jj][b]);
      arz[1][jj][b] = rsum32(arz[1][jj][b]);
      axn[jj][b] = rsum32(axn[jj][b]);
      ahn[jj][b] = rsum32(ahn[jj][b]);
    }
  if (ks == 0) {
#pragma unroll
    for (int jj = 0; jj < 2; ++jj) {
      int j = j0 + jj;
      float bhr = bhh[j], bhz = bhh[1024 + j], bhn = bhh[2048 + j];
#pragma unroll
      for (int b = 0; b < 8; ++b) {
        int rowi = t * 32 + b0 + b;
        const float* gie = gi_e + (size_t)rowi * 3072 + j;
        float r = sigm(gie[0] + arz[0][jj][b] + bhr);
        float z = sigm(gie[1024] + arz[1][jj][b] + bhz);
        float n = tanhf(gie[2048] + axn[jj][b] + r * (ahn[jj][b] + bhn));
        h2ctx[(size_t)rowi * 2048 + j] = (1.f - z) * n + z * hs[b][j];
      }
    }
  }
}

// ---------------------------------------------------------------------------
__global__ void k_gather_e(const int* __restrict__ toks, const float* __restrict__ emb,
                           float* __restrict__ e_all)
{
  int row = blockIdx.x;               // 2048
  int t = row >> 5, b = row & 31;
  float* dst = e_all + (size_t)row * 1024 + threadIdx.x * 4;
  if (t < 63) {
    int tok = toks[b * 64 + t];
    *(f32x4*)dst = *(const f32x4*)(emb + (size_t)tok * 1024 + threadIdx.x * 4);
  } else {
    *(f32x4*)dst = (f32x4){0.f, 0.f, 0.f, 0.f};
  }
}

__global__ void k_zero(float* __restrict__ p)
{
  p[blockIdx.x * 256 + threadIdx.x] = 0.f;
}

__global__ void k_onehot(const int* __restrict__ toks, float* __restrict__ out)
{
  int i = blockIdx.x * 256 + threadIdx.x;
  if (i >= 32 * 32000) return;
  int b = i / 32000, v = i - b * 32000;
  out[(size_t)b * 64 * 32000 + v] = (v == toks[0]) ? 1.0f : 0.0f;
}

// ---------------------------------------------------------------------------
extern "C" void kernel_launch(void* const* d_in, const int* in_sizes, int n_in,
                              void* d_out, int out_size, void* d_ws, size_t ws_size,
                              hipStream_t stream)
{
  const float* features = (const float*)d_in[0];
  const int*   toks     = (const int*)d_in[1];
  const float* temp_W = (const float*)d_in[2];  const float* temp_b = (const float*)d_in[3];
  const float* hum_W  = (const float*)d_in[4];  const float* hum_b  = (const float*)d_in[5];
  const float* cloud_W= (const float*)d_in[6];  const float* cloud_b= (const float*)d_in[7];
  const float* time_W = (const float*)d_in[8];  const float* time_b = (const float*)d_in[9];
  const float* other_W= (const float*)d_in[10]; const float* other_b= (const float*)d_in[11];
  const float* fi_W   = (const float*)d_in[12]; const float* fi_b   = (const float*)d_in[13];
  const float* enc_wih= (const float*)d_in[14]; const float* enc_whh= (const float*)d_in[15];
  const float* enc_bih= (const float*)d_in[16]; const float* enc_bhh= (const float*)d_in[17];
  const float* emb    = (const float*)d_in[18];
  const float* attn_W = (const float*)d_in[19]; const float* attn_b = (const float*)d_in[20];
  const float* dec_wih= (const float*)d_in[21]; const float* dec_whh= (const float*)d_in[22];
  const float* dec_bih= (const float*)d_in[23]; const float* dec_bhh= (const float*)d_in[24];
  const float* out_W  = (const float*)d_in[25]; const float* out_b  = (const float*)d_in[26];
  float* out = (float*)d_out;
  char* ws = (char*)d_ws;

  float* Mf      = (float*)(ws + 0);
  float* b0v     = (float*)(ws + 65536);
  float* proj    = (float*)(ws + 69632);
  float* gi_all  = (float*)(ws + 16846848);
  float* enc_out = (float*)(ws + 67178496);
  float* keys    = (float*)(ws + 83955712);
  float* e_all   = (float*)(ws + 100732928);
  float* gi_e    = (float*)(ws + 109121536);
  float* h2ctx   = (float*)(ws + 134287360);
  unsigned short* whhE = (unsigned short*)(ws + 151064576);
  unsigned short* whhD = (unsigned short*)(ws + 157356032);
  unsigned short* wih2 = (unsigned short*)(ws + 163647488);

  // weight conversions (bf16 for the recurrent matvecs)
  k_tobf4<<<3072, 256, 0, stream>>>(enc_whh, whhE, 786432);
  k_tobf4<<<3072, 256, 0, stream>>>(dec_whh, whhD, 786432);
  k_tobf_wih2<<<3072, 256, 0, stream>>>(dec_wih, wih2);

  // feature pipeline
  k_fold<<<68, 256, 0, stream>>>(temp_W, temp_b, hum_W, hum_b, cloud_W, cloud_b,
                                 time_W, time_b, other_W, other_b, fi_W, fi_b, Mf, b0v);
  k_proj<<<dim3(4096, 4), 256, 0, stream>>>(features, Mf, b0v, proj);

  // encoder input gates (batched)
  gemm_bt<0><<<32 * 24, 256, 0, stream>>>(proj, enc_wih, enc_bih, gi_all,
                                          4096, 3072, 1024, 1024, 1024, 3072);
  // encoder scan
  for (int s = 0; s < 128; ++s)
    k_enc_step<<<dim3(64, 4), 256, 0, stream>>>(gi_all, whhE, enc_bhh, enc_out, s);

  // attention keys
  gemm_bt<0><<<32 * 8, 256, 0, stream>>>(enc_out, attn_W, attn_b, keys,
                                         4096, 1024, 1024, 1024, 1024, 1024);
  // decoder embedding-path gates (batched, teacher forcing)
  k_gather_e<<<2048, 256, 0, stream>>>(toks, emb, e_all);
  gemm_bt<0><<<16 * 24, 256, 0, stream>>>(e_all, dec_wih, dec_bih, gi_e,
                                          2048, 3072, 1024, 1024, 2048, 3072);
  // zero padding rows of h2ctx (rows 2016..2047)
  k_zero<<<256, 256, 0, stream>>>(h2ctx + (size_t)2016 * 2048);

  // decoder scan
  for (int t = 0; t < 63; ++t) {
    const float* h_in = (t == 0) ? (enc_out + (size_t)127 * 1024)
                                 : (h2ctx + (size_t)(t - 1) * 32 * 2048);
    int hstr = (t == 0) ? (128 * 1024) : 2048;
    k_dec_attn<<<32, 256, 0, stream>>>(h_in, hstr, keys, enc_out, h2ctx, t);
    k_dec_gru<<<dim3(64, 4), 256, 0, stream>>>(h_in, hstr, gi_e, wih2, whhD, dec_bhh, h2ctx, t);
  }

  // batched output projection -> out[:, 1:, :]
  gemm_bt<1><<<16 * 250, 256, 0, stream>>>(h2ctx, out_W, out_b, out,
                                           2048, 32000, 2048, 2048, 2048, 0);
  // out[:, 0, :] one-hot
  k_onehot<<<4000, 256, 0, stream>>>(toks, out);
}

// Round 2
// 4371.503 us; speedup vs baseline: 2.0090x; 2.0090x over previous
//
#include <hip/hip_runtime.h>

typedef float f32x4 __attribute__((ext_vector_type(4)));
typedef __bf16 bf16x8 __attribute__((ext_vector_type(8)));

#define DI static __device__ __forceinline__

DI unsigned short f2bf(float f) {
  unsigned u = __float_as_uint(f);
  u = (u + 0x7fffu + ((u >> 16) & 1u)) >> 16;
  return (unsigned short)u;
}
DI unsigned pk2(float lo, float hi) {
  return (unsigned)f2bf(lo) | ((unsigned)f2bf(hi) << 16);
}
DI float bflo(unsigned u) { return __uint_as_float(u << 16); }
DI float bfhi(unsigned u) { return __uint_as_float(u & 0xffff0000u); }
DI float sigm(float x) { return 1.0f / (1.0f + expf(-x)); }

DI void gl_lds16(const unsigned short* g, unsigned short* l) {
  __builtin_amdgcn_global_load_lds(
      (const __attribute__((address_space(1))) unsigned int*)g,
      (__attribute__((address_space(3))) unsigned int*)l, 16, 0, 0);
}

// device-scope grid barrier on a per-use counter (zeroed before launch)
DI void gridbar(int* c, int nblk) {
  __syncthreads();
  if (threadIdx.x == 0) {
    __threadfence();
    __hip_atomic_fetch_add(c, 1, __ATOMIC_RELAXED, __HIP_MEMORY_SCOPE_AGENT);
    while (__hip_atomic_load(c, __ATOMIC_RELAXED, __HIP_MEMORY_SCOPE_AGENT) < nblk)
      __builtin_amdgcn_s_sleep(1);
    __threadfence();
  }
  __syncthreads();
}

// ---------------------------------------------------------------------------
// Fold tiny per-feature projections + fi into M[1024][16], b0[1024]
// ---------------------------------------------------------------------------
__global__ void k_fold(const float* __restrict__ tW, const float* __restrict__ tb,
                       const float* __restrict__ hW, const float* __restrict__ hb,
                       const float* __restrict__ cW, const float* __restrict__ cb,
                       const float* __restrict__ tiW, const float* __restrict__ tib,
                       const float* __restrict__ oW, const float* __restrict__ ob,
                       const float* __restrict__ fiW, const float* __restrict__ fib,
                       float* __restrict__ M, float* __restrict__ b0v)
{
  int g = blockIdx.x * 256 + threadIdx.x;
  if (g >= 1024 * 17) return;
  int h = g / 17, f = g - h * 17;
  const float* fw = fiW + (size_t)h * 2048;
  float s = 0.f;
  if (f == 16) {
    for (int k = 0; k < 256; ++k) s += fw[k] * tb[k];
    for (int k = 0; k < 256; ++k) s += fw[256 + k] * hb[k];
    for (int k = 0; k < 256; ++k) s += fw[512 + k] * cb[k];
    for (int k = 0; k < 256; ++k) s += fw[768 + k] * tib[k];
    for (int r = 0; r < 1024; ++r) s += fw[1024 + r] * ob[r];
    b0v[h] = s + fib[h];
  } else if (f == 0) {
    for (int k = 0; k < 256; ++k) s += fw[k] * tW[k];
    M[h * 16 + 0] = s;
  } else if (f == 1) {
    for (int k = 0; k < 256; ++k) s += fw[256 + k] * hW[k];
    M[h * 16 + 1] = s;
  } else if (f == 2) {
    for (int k = 0; k < 256; ++k) s += fw[512 + k] * cW[k];
    M[h * 16 + 2] = s;
  } else if (f == 11) {
    for (int k = 0; k < 256; ++k) s += fw[768 + k] * tiW[2 * k];
    M[h * 16 + 11] = s;
  } else if (f == 12) {
    for (int k = 0; k < 256; ++k) s += fw[768 + k] * tiW[2 * k + 1];
    M[h * 16 + 12] = s;
  } else {
    int col = (f <= 10) ? (f - 3) : (f - 5);
    for (int r = 0; r < 1024; ++r) s += fw[1024 + r] * oW[r * 11 + col];
    M[h * 16 + f] = s;
  }
}

__global__ __launch_bounds__(256)
void k_proj(const float* __restrict__ feat, const float* __restrict__ M,
            const float* __restrict__ b0v, unsigned short* __restrict__ proj)
{
  __shared__ float ft[16];
  int bs = blockIdx.x;
  int h = blockIdx.y * 256 + threadIdx.x;
  if (threadIdx.x < 16) ft[threadIdx.x] = feat[bs * 16 + threadIdx.x];
  __syncthreads();
  float sum = b0v[h];
  const float* mr = M + h * 16;
#pragma unroll
  for (int f = 0; f < 16; ++f) sum += mr[f] * ft[f];
  proj[(size_t)bs * 1024 + h] = f2bf(tanhf(sum));
}

// ---------------------------------------------------------------------------
// fp32 -> bf16 converters
// ---------------------------------------------------------------------------
__global__ void k_conv(const float* __restrict__ s, unsigned short* __restrict__ d, int n8)
{
  for (long i = (long)blockIdx.x * 256 + threadIdx.x; i < n8; i += (long)gridDim.x * 256) {
    const float* p = s + i * 8;
    f32x4 a = *(const f32x4*)p, b = *(const f32x4*)(p + 4);
    uint4 o;
    o.x = pk2(a[0], a[1]); o.y = pk2(a[2], a[3]);
    o.z = pk2(b[0], b[1]); o.w = pk2(b[2], b[3]);
    *(uint4*)(d + i * 8) = o;
  }
}

// rows x 1024 from a ld-2048 matrix (col offset 0)
__global__ void k_conv_str(const float* __restrict__ s, unsigned short* __restrict__ d)
{
  int r = blockIdx.x;
  int c = threadIdx.x * 4;
  f32x4 a = *(const f32x4*)(s + (size_t)r * 2048 + c);
  uint2 o; o.x = pk2(a[0], a[1]); o.y = pk2(a[2], a[3]);
  *(uint2*)(d + (size_t)r * 1024 + c) = o;
}

__global__ void k_gather_e(const int* __restrict__ toks, const float* __restrict__ emb,
                           unsigned short* __restrict__ e_bf)
{
  int row = blockIdx.x;               // 2048
  int t = row >> 5, b = row & 31;
  unsigned short* dst = e_bf + (size_t)row * 1024 + threadIdx.x * 4;
  if (t < 63) {
    int tok = toks[b * 64 + t];
    f32x4 a = *(const f32x4*)(emb + (size_t)tok * 1024 + threadIdx.x * 4);
    uint2 o; o.x = pk2(a[0], a[1]); o.y = pk2(a[2], a[3]);
    *(uint2*)dst = o;
  } else {
    uint2 o; o.x = 0u; o.y = 0u;
    *(uint2*)dst = o;
  }
}

__global__ void k_onehot(const int* __restrict__ toks, float* __restrict__ out)
{
  int i = blockIdx.x * 256 + threadIdx.x;
  if (i >= 32 * 32000) return;
  int b = i / 32000, v = i - b * 32000;
  out[(size_t)b * 64 * 32000 + v] = (v == toks[0]) ? 1.0f : 0.0f;
}

// ---------------------------------------------------------------------------
// bf16 MFMA GEMM, m97 structure: C[M,N] = A[M,K] * B[N,K]^T + bias[N]
// A,B pre-converted bf16. 128x128 tile, BK=32, global_load_lds width 16.
// MODE 0: f32 C[r*ldc+c]; MODE 1: bf16 out; MODE 2: decoder-output remap.
// ---------------------------------------------------------------------------
template<int MODE>
__global__ __launch_bounds__(256)
void gemm_bf(const unsigned short* __restrict__ A, const unsigned short* __restrict__ B,
             const float* __restrict__ bias, float* __restrict__ Cf,
             unsigned short* __restrict__ Cb,
             int tiles_m, int K, int lda, int ldb, int ldc, int coloff)
{
  __shared__ unsigned short As[4096];
  __shared__ unsigned short Bs[4096];
  const int nblk = gridDim.x;
  const int cpx = nblk >> 3;
  const int bid = blockIdx.x;
  const int id = (bid & 7) * cpx + (bid >> 3);     // XCD-contiguous work ids
  const int tm = id % tiles_m, tn = id / tiles_m;
  const int tid = threadIdx.x;
  const int lane = tid & 63, wave = tid >> 6;
  const int wm = (wave & 1) << 6, wn = (wave >> 1) << 6;
  const int r0 = tid >> 2, kc0 = (tid & 3) << 3;
  const unsigned short* ga0 = A + (size_t)(tm * 128 + r0) * lda + kc0;
  const unsigned short* ga1 = A + (size_t)(tm * 128 + 64 + r0) * lda + kc0;
  const unsigned short* gb0 = B + (size_t)(tn * 128 + r0) * ldb + kc0;
  const unsigned short* gb1 = B + (size_t)(tn * 128 + 64 + r0) * ldb + kc0;
  const int lr = lane & 15, lkb = (lane >> 4) << 3;

  f32x4 acc[4][4];
#pragma unroll
  for (int m = 0; m < 4; ++m)
#pragma unroll
    for (int n = 0; n < 4; ++n) { acc[m][n][0]=0.f; acc[m][n][1]=0.f; acc[m][n][2]=0.f; acc[m][n][3]=0.f; }

  for (int kt = 0; kt < K; kt += 32) {
    __syncthreads();
    gl_lds16(ga0 + kt, &As[tid * 8]);
    gl_lds16(ga1 + kt, &As[(tid + 256) * 8]);
    gl_lds16(gb0 + kt, &Bs[tid * 8]);
    gl_lds16(gb1 + kt, &Bs[(tid + 256) * 8]);
    __syncthreads();
    bf16x8 af[4], bfv[4];
#pragma unroll
    for (int m = 0; m < 4; ++m) af[m] = *(const bf16x8*)&As[(wm + m * 16 + lr) * 32 + lkb];
#pragma unroll
    for (int n = 0; n < 4; ++n) bfv[n] = *(const bf16x8*)&Bs[(wn + n * 16 + lr) * 32 + lkb];
#pragma unroll
    for (int m = 0; m < 4; ++m)
#pragma unroll
      for (int n = 0; n < 4; ++n)
        acc[m][n] = __builtin_amdgcn_mfma_f32_16x16x32_bf16(af[m], bfv[n], acc[m][n], 0, 0, 0);
  }

#pragma unroll
  for (int m = 0; m < 4; ++m) {
    int rb = tm * 128 + wm + m * 16 + ((lane >> 4) << 2);
#pragma unroll
    for (int n = 0; n < 4; ++n) {
      int c = tn * 128 + wn + n * 16 + lr;
      float bb = bias[c];
#pragma unroll
      for (int i = 0; i < 4; ++i) {
        float v = acc[m][n][i] + bb;
        int r = rb + i;
        if (MODE == 0) {
          Cf[(size_t)r * ldc + c] = v;
        } else if (MODE == 1) {
          Cb[(size_t)r * ldc + c] = f2bf(v);
        } else {
          if (r < 2016) {
            int t = r >> 5, b2 = r & 31;
            Cf[((size_t)b2 * 64 + t + 1) * 32000 + coloff + c] = v;
          }
        }
      }
    }
  }
}

// ---------------------------------------------------------------------------
// Persistent encoder scan. 64 blocks x 256. Block owns 16 j's (48 whh rows in
// LDS, bf16, XOR-swizzled). Per step: C[32,48] = h_bf x W^T via MFMA (k-split
// over 4 waves), LDS reduce, gates, write h (fp32+bf16) + enc_bf, grid barrier.
// ---------------------------------------------------------------------------
__global__ __launch_bounds__(256, 1)
void k_enc_scan(const float* __restrict__ gi_all, const float* __restrict__ whh,
                const float* __restrict__ bhh, unsigned short* __restrict__ hbf,
                float* __restrict__ hfp, unsigned short* __restrict__ enc_bf,
                int* __restrict__ cnt)
{
  __shared__ unsigned short W[48 * 1024];
  __shared__ float Cred[4 * 2 * 3 * 64 * 4];
  const int tid = threadIdx.x;
  const int lane = tid & 63, wave = tid >> 6;
  const int j0 = blockIdx.x * 16;

  // stage 48 weight rows (r16,z16,n16) into LDS as bf16, XOR-swizzled chunks
  for (int i = tid; i < 48 * 128; i += 256) {
    int r = i >> 7, c = i & 127;
    int gr = ((r >> 4) << 10) + j0 + (r & 15);
    const float* src = whh + ((size_t)gr << 10) + (c << 3);
    f32x4 a = *(const f32x4*)src, b = *(const f32x4*)(src + 4);
    uint4 o;
    o.x = pk2(a[0], a[1]); o.y = pk2(a[2], a[3]);
    o.z = pk2(b[0], b[1]); o.w = pk2(b[2], b[3]);
    *(uint4*)&W[(r << 10) + ((c ^ (r & 7)) << 3)] = o;
  }
  __syncthreads();

  // per-thread gate cell decomposition (2 cells)
  int cb[2], cj[2], clb[2], creg[2], cm[2];
  float bh0[2], bh1[2], bh2[2];
#pragma unroll
  for (int cc = 0; cc < 2; ++cc) {
    int cell = tid + (cc << 8);
    cb[cc] = cell >> 4; cj[cc] = cell & 15;
    clb[cc] = ((cb[cc] & 15) >> 2) * 16;
    creg[cc] = cb[cc] & 3; cm[cc] = cb[cc] >> 4;
    bh0[cc] = bhh[j0 + cj[cc]];
    bh1[cc] = bhh[1024 + j0 + cj[cc]];
    bh2[cc] = bhh[2048 + j0 + cj[cc]];
  }

#pragma unroll 1
  for (int s = 0; s < 128; ++s) {
    const int rb = s & 1, wb = rb ^ 1;
    const unsigned short* hr = hbf + rb * 32768;

    // prefetch gi + h_prev for gate phase
    float gp[2][3], hp[2];
#pragma unroll
    for (int cc = 0; cc < 2; ++cc) {
      const float* gi = gi_all + ((size_t)cb[cc] * 128 + s) * 3072 + j0 + cj[cc];
      gp[cc][0] = gi[0]; gp[cc][1] = gi[1024]; gp[cc][2] = gi[2048];
      hp[cc] = hfp[rb * 32768 + cb[cc] * 1024 + j0 + cj[cc]];
    }

    // MFMA phase, wave handles k range [wave*256, wave*256+256)
    const int k0 = wave << 8;
    bf16x8 af[2][8];
#pragma unroll
    for (int kk = 0; kk < 8; ++kk) {
      int k = k0 + kk * 32 + ((lane >> 4) << 3);
      af[0][kk] = *(const bf16x8*)(hr + (size_t)(lane & 15) * 1024 + k);
      af[1][kk] = *(const bf16x8*)(hr + (size_t)(16 + (lane & 15)) * 1024 + k);
    }
    f32x4 acc[2][3];
#pragma unroll
    for (int m = 0; m < 2; ++m)
#pragma unroll
      for (int n = 0; n < 3; ++n) { acc[m][n][0]=0.f; acc[m][n][1]=0.f; acc[m][n][2]=0.f; acc[m][n][3]=0.f; }
#pragma unroll
    for (int kk = 0; kk < 8; ++kk) {
      int c = ((k0 + kk * 32) >> 3) + (lane >> 4);
#pragma unroll
      for (int n = 0; n < 3; ++n) {
        int wr = n * 16 + (lane & 15);
        bf16x8 bfr = *(const bf16x8*)&W[(wr << 10) + ((c ^ (wr & 7)) << 3)];
        acc[0][n] = __builtin_amdgcn_mfma_f32_16x16x32_bf16(af[0][kk], bfr, acc[0][n], 0, 0, 0);
        acc[1][n] = __builtin_amdgcn_mfma_f32_16x16x32_bf16(af[1][kk], bfr, acc[1][n], 0, 0, 0);
      }
    }
#pragma unroll
    for (int m = 0; m < 2; ++m)
#pragma unroll
      for (int n = 0; n < 3; ++n)
        *(f32x4*)&Cred[((((wave * 2 + m) * 3 + n) * 64) + lane) << 2] = acc[m][n];
    __syncthreads();

    // gate phase: 2 cells/thread
#pragma unroll
    for (int cc = 0; cc < 2; ++cc) {
      int b = cb[cc], j = cj[cc];
      int lj = clb[cc] + j, reg = creg[cc], m = cm[cc];
      float Cr = 0.f, Cz = 0.f, Cn = 0.f;
#pragma unroll
      for (int w = 0; w < 4; ++w) {
        Cr += Cred[((((w * 2 + m) * 3 + 0) * 64 + lj) << 2) + reg];
        Cz += Cred[((((w * 2 + m) * 3 + 1) * 64 + lj) << 2) + reg];
        Cn += Cred[((((w * 2 + m) * 3 + 2) * 64 + lj) << 2) + reg];
      }
      float r = sigm(gp[cc][0] + Cr + bh0[cc]);
      float z = sigm(gp[cc][1] + Cz + bh1[cc]);
      float n = tanhf(gp[cc][2] + r * (Cn + bh2[cc]));
      float h2 = (1.f - z) * n + z * hp[cc];
      hfp[wb * 32768 + b * 1024 + j0 + j] = h2;
      unsigned short hb16 = f2bf(h2);
      hbf[wb * 32768 + b * 1024 + j0 + j] = hb16;
      enc_bf[((size_t)b * 128 + s) * 1024 + j0 + j] = hb16;
    }
    gridbar(&cnt[s], 64);
  }
}

// ---------------------------------------------------------------------------
// Persistent decoder scan. 128 blocks x 256. Block owns 8 j's (24+8pad rows
// of whhD and of wih2 in LDS bf16). Per step: attn (blocks 0..31, per-batch
// scores+softmax+ctx), barrier, GRU via MFMA (waves 0-1: h-part, 2-3:
// ctx-part), gates, barrier.
// ---------------------------------------------------------------------------
__global__ __launch_bounds__(256, 1)
void k_dec_scan(const float* __restrict__ gi_e, const float* __restrict__ whh,
                const float* __restrict__ wih, const float* __restrict__ bhh,
                const unsigned short* __restrict__ keys,
                const unsigned short* __restrict__ enc_bf,
                unsigned short* __restrict__ hcat, float* __restrict__ hfp,
                const unsigned short* __restrict__ hbf0, int* __restrict__ cnt)
{
  __shared__ unsigned short Wh[32 * 1024];
  __shared__ unsigned short Wx[32 * 1024];
  __shared__ float Cred[4 * 2 * 2 * 64 * 4];
  __shared__ unsigned short hsh[1024];
  __shared__ float sarr[128];
  __shared__ float earr[128];
  const int tid = threadIdx.x;
  const int lane = tid & 63, wave = tid >> 6;
  const int blk = blockIdx.x;
  const int j0 = blk * 8;

  // stage weights: rows 0-7 r, 8-15 z, 16-23 n, 24-31 zero
  for (int i = tid; i < 32 * 128; i += 256) {
    int r = i >> 7, c = i & 127;
    int off = (r << 10) + ((c ^ (r & 7)) << 3);
    uint4 oh, ox;
    oh.x = oh.y = oh.z = oh.w = 0u; ox = oh;
    if (r < 24) {
      int gr = ((r >> 3) << 10) + j0 + (r & 7);
      const float* sh = whh + ((size_t)gr << 10) + (c << 3);
      f32x4 a = *(const f32x4*)sh, b = *(const f32x4*)(sh + 4);
      oh.x = pk2(a[0], a[1]); oh.y = pk2(a[2], a[3]);
      oh.z = pk2(b[0], b[1]); oh.w = pk2(b[2], b[3]);
      const float* sx = wih + ((size_t)gr << 11) + 1024 + (c << 3);
      f32x4 e = *(const f32x4*)sx, f = *(const f32x4*)(sx + 4);
      ox.x = pk2(e[0], e[1]); ox.y = pk2(e[2], e[3]);
      ox.z = pk2(f[0], f[1]); ox.w = pk2(f[2], f[3]);
    }
    *(uint4*)&Wh[off] = oh;
    *(uint4*)&Wx[off] = ox;
  }
  __syncthreads();

  // gate cell decomposition (1 cell/thread)
  const int gb = tid >> 3, gj = tid & 7;
  const int glb = ((gb & 15) >> 2) * 16;
  const int greg = gb & 3, gm = gb >> 4;
  const float bh0 = bhh[j0 + gj];
  const float bh1 = bhh[1024 + j0 + gj];
  const float bh2 = bhh[2048 + j0 + gj];

#pragma unroll 1
  for (int t = 0; t < 63; ++t) {
    const int rb = t & 1, wb = rb ^ 1;

    // ---------------- attention (blocks 0..31: one per batch) -------------
    if (blk < 32) {
      const int b = blk;
      const unsigned short* hsrc = (t == 0) ? (hbf0 + b * 1024)
                                            : (hcat + ((size_t)(t - 1) * 32 + b) * 2048);
      *(uint2*)&hsh[tid * 4] = *(const uint2*)(hsrc + tid * 4);
      __syncthreads();
      {
        int sp = tid >> 1, kh = (tid & 1) << 9;
        const unsigned short* kr = keys + ((size_t)b * 128 + sp) * 1024 + kh;
        float a = 0.f;
#pragma unroll 8
        for (int c = 0; c < 512; c += 8) {
          uint4 kv = *(const uint4*)(kr + c);
          uint4 hv = *(const uint4*)&hsh[kh + c];
          a += bflo(kv.x) * bflo(hv.x) + bfhi(kv.x) * bfhi(hv.x)
             + bflo(kv.y) * bflo(hv.y) + bfhi(kv.y) * bfhi(hv.y)
             + bflo(kv.z) * bflo(hv.z) + bfhi(kv.z) * bfhi(hv.z)
             + bflo(kv.w) * bflo(hv.w) + bfhi(kv.w) * bfhi(hv.w);
        }
        a += __shfl_xor(a, 1);
        if ((tid & 1) == 0) sarr[sp] = a * 0.03125f;
      }
      __syncthreads();
      float mx = -1e30f;
#pragma unroll 16
      for (int i2 = 0; i2 < 128; ++i2) mx = fmaxf(mx, sarr[i2]);
      if (tid < 128) earr[tid] = expf(sarr[tid] - mx);
      __syncthreads();
      float sum = 0.f;
#pragma unroll 16
      for (int i2 = 0; i2 < 128; ++i2) sum += earr[i2];
      float winv = 1.f / sum;
      f32x4 cacc; cacc[0]=0.f; cacc[1]=0.f; cacc[2]=0.f; cacc[3]=0.f;
      const unsigned short* eb = enc_bf + ((size_t)b << 17) + tid * 4;
#pragma unroll 4
      for (int s2 = 0; s2 < 128; ++s2) {
        float w = earr[s2] * winv;
        uint2 ev = *(const uint2*)(eb + ((size_t)s2 << 10));
        cacc[0] += w * bflo(ev.x); cacc[1] += w * bfhi(ev.x);
        cacc[2] += w * bflo(ev.y); cacc[3] += w * bfhi(ev.y);
      }
      uint2 co; co.x = pk2(cacc[0], cacc[1]); co.y = pk2(cacc[2], cacc[3]);
      *(uint2*)(hcat + ((size_t)t * 32 + b) * 2048 + 1024 + tid * 4) = co;
    }
    gridbar(&cnt[128 + t * 2], 128);

    // ---------------- GRU phase ------------------------------------------
    // prefetch gi_e + h_prev
    const float* gie = gi_e + ((size_t)t * 32 + gb) * 3072 + j0 + gj;
    float g0 = gie[0], g1 = gie[1024], g2 = gie[2048];
    float hpv = hfp[rb * 32768 + gb * 1024 + j0 + gj];

    const int part = wave >> 1;
    const int kh2 = (wave & 1) << 9;
    const unsigned short* abase;
    size_t astr;
    if (part == 0) {
      if (t == 0) { abase = hbf0; astr = 1024; }
      else { abase = hcat + (size_t)(t - 1) * 32 * 2048; astr = 2048; }
    } else {
      abase = hcat + (size_t)t * 32 * 2048 + 1024; astr = 2048;
    }
    const unsigned short* Wl = part ? Wx : Wh;
    f32x4 acc[2][2];
#pragma unroll
    for (int m = 0; m < 2; ++m)
#pragma unroll
      for (int n = 0; n < 2; ++n) { acc[m][n][0]=0.f; acc[m][n][1]=0.f; acc[m][n][2]=0.f; acc[m][n][3]=0.f; }
#pragma unroll
    for (int hh = 0; hh < 2; ++hh) {
      bf16x8 af[2][8];
#pragma unroll
      for (int kk = 0; kk < 8; ++kk) {
        int k = kh2 + hh * 256 + kk * 32 + ((lane >> 4) << 3);
        af[0][kk] = *(const bf16x8*)(abase + (size_t)(lane & 15) * astr + k);
        af[1][kk] = *(const bf16x8*)(abase + (size_t)(16 + (lane & 15)) * astr + k);
      }
#pragma unroll
      for (int kk = 0; kk < 8; ++kk) {
        int c = ((kh2 + hh * 256 + kk * 32) >> 3) + (lane >> 4);
#pragma unroll
        for (int n = 0; n < 2; ++n) {
          int wr = n * 16 + (lane & 15);
          bf16x8 bfr = *(const bf16x8*)&Wl[(wr << 10) + ((c ^ (wr & 7)) << 3)];
          acc[0][n] = __builtin_amdgcn_mfma_f32_16x16x32_bf16(af[0][kk], bfr, acc[0][n], 0, 0, 0);
          acc[1][n] = __builtin_amdgcn_mfma_f32_16x16x32_bf16(af[1][kk], bfr, acc[1][n], 0, 0, 0);
        }
      }
    }
#pragma unroll
    for (int m = 0; m < 2; ++m)
#pragma unroll
      for (int n = 0; n < 2; ++n)
        *(f32x4*)&Cred[((((wave * 2 + m) * 2 + n) * 64) + lane) << 2] = acc[m][n];
    __syncthreads();

    // gates: 1 cell/thread
    {
      float Chr = 0.f, Chz = 0.f, Chn = 0.f, Cxr = 0.f, Cxz = 0.f, Cxn = 0.f;
#pragma unroll
      for (int w = 0; w < 2; ++w) {
        Chr += Cred[((((w * 2 + gm) * 2 + 0) * 64 + glb + gj) << 2) + greg];
        Chz += Cred[((((w * 2 + gm) * 2 + 0) * 64 + glb + gj + 8) << 2) + greg];
        Chn += Cred[((((w * 2 + gm) * 2 + 1) * 64 + glb + gj) << 2) + greg];
        Cxr += Cred[(((((w + 2) * 2 + gm) * 2 + 0) * 64 + glb + gj) << 2) + greg];
        Cxz += Cred[(((((w + 2) * 2 + gm) * 2 + 0) * 64 + glb + gj + 8) << 2) + greg];
        Cxn += Cred[(((((w + 2) * 2 + gm) * 2 + 1) * 64 + glb + gj) << 2) + greg];
      }
      float r = sigm(g0 + Cxr + Chr + bh0);
      float z = sigm(g1 + Cxz + Chz + bh1);
      float n2 = tanhf(g2 + Cxn + r * (Chn + bh2));
      float h2 = (1.f - z) * n2 + z * hpv;
      hfp[wb * 32768 + gb * 1024 + j0 + gj] = h2;
      hcat[((size_t)t * 32 + gb) * 2048 + j0 + gj] = f2bf(h2);
    }
    gridbar(&cnt[128 + t * 2 + 1], 128);
  }
}

// ---------------------------------------------------------------------------
extern "C" void kernel_launch(void* const* d_in, const int* in_sizes, int n_in,
                              void* d_out, int out_size, void* d_ws, size_t ws_size,
                              hipStream_t stream)
{
  const float* features = (const float*)d_in[0];
  const int*   toks     = (const int*)d_in[1];
  const float* temp_W = (const float*)d_in[2];  const float* temp_b = (const float*)d_in[3];
  const float* hum_W  = (const float*)d_in[4];  const float* hum_b  = (const float*)d_in[5];
  const float* cloud_W= (const float*)d_in[6];  const float* cloud_b= (const float*)d_in[7];
  const float* time_W = (const float*)d_in[8];  const float* time_b = (const float*)d_in[9];
  const float* other_W= (const float*)d_in[10]; const float* other_b= (const float*)d_in[11];
  const float* fi_W   = (const float*)d_in[12]; const float* fi_b   = (const float*)d_in[13];
  const float* enc_wih= (const float*)d_in[14]; const float* enc_whh= (const float*)d_in[15];
  const float* enc_bih= (const float*)d_in[16]; const float* enc_bhh= (const float*)d_in[17];
  const float* emb    = (const float*)d_in[18];
  const float* attn_W = (const float*)d_in[19]; const float* attn_b = (const float*)d_in[20];
  const float* dec_wih= (const float*)d_in[21]; const float* dec_whh= (const float*)d_in[22];
  const float* dec_bih= (const float*)d_in[23]; const float* dec_bhh= (const float*)d_in[24];
  const float* out_W  = (const float*)d_in[25]; const float* out_b  = (const float*)d_in[26];
  float* out = (float*)d_out;
  char* ws = (char*)d_ws;

  int*            cnt     = (int*)(ws + 0);                        // 4 KB
  float*          Mf      = (float*)(ws + 4096);                   // 64 KB
  float*          b0v     = (float*)(ws + 69632);                  // 4 KB
  float*          hfp     = (float*)(ws + 73728);                  // 256 KB
  unsigned short* hbf     = (unsigned short*)(ws + 335872);        // 128 KB
  unsigned short* hcat    = (unsigned short*)(ws + 466944);        // 8 MB  [2048][2048]
  unsigned short* keys_bf = (unsigned short*)(ws + 8855552);       // 8 MB
  unsigned short* enc_bf  = (unsigned short*)(ws + 17244160);      // 8 MB
  float*          gi_e    = (float*)(ws + 25632768);               // 24 MB
  float*          gi_all  = (float*)(ws + 50798592);               // 48 MB
  unsigned short* proj_bf = (unsigned short*)(ws + 101130240);     // 8 MB
  unsigned short* e_bf    = (unsigned short*)(ws + 109518848);     // 4 MB
  unsigned short* wihE_bf = (unsigned short*)(ws + 113713152);     // 6 MB
  unsigned short* attnW_bf= (unsigned short*)(ws + 120004608);     // 2 MB
  unsigned short* wihD_bf = (unsigned short*)(ws + 122101760);     // 6 MB
  // out_W bf16 halves alias the (dead-by-then) gi_e/gi_all region
  unsigned short* outW_bf = (unsigned short*)(ws + 25632768);      // 62.5 MB

  // zero barrier counters, h state, hcat padding rows (2016..2047)
  hipMemsetAsync(ws, 0, 4096, stream);
  hipMemsetAsync(ws + 73728, 0, 262144 + 131072, stream);
  hipMemsetAsync(ws + 466944 + (size_t)2016 * 2048 * 2, 0, 32 * 2048 * 2, stream);

  // weight conversions
  k_conv<<<1536, 256, 0, stream>>>(enc_wih, wihE_bf, 393216);
  k_conv<<<512, 256, 0, stream>>>(attn_W, attnW_bf, 131072);
  k_conv_str<<<3072, 256, 0, stream>>>(dec_wih, wihD_bf);

  // feature pipeline
  k_fold<<<68, 256, 0, stream>>>(temp_W, temp_b, hum_W, hum_b, cloud_W, cloud_b,
                                 time_W, time_b, other_W, other_b, fi_W, fi_b, Mf, b0v);
  k_proj<<<dim3(4096, 4), 256, 0, stream>>>(features, Mf, b0v, proj_bf);

  // encoder input gates (batched): gi_all[4096,3072]
  gemm_bf<0><<<768, 256, 0, stream>>>(proj_bf, wihE_bf, enc_bih, gi_all, nullptr,
                                      32, 1024, 1024, 1024, 3072, 0);
  // encoder scan (persistent)
  k_enc_scan<<<64, 256, 0, stream>>>(gi_all, enc_whh, enc_bhh, hbf, hfp, enc_bf, cnt);

  // attention keys (bf16 out)
  gemm_bf<1><<<256, 256, 0, stream>>>(enc_bf, attnW_bf, attn_b, nullptr, keys_bf,
                                      32, 1024, 1024, 1024, 1024, 0);
  // decoder embedding-path gates
  k_gather_e<<<2048, 256, 0, stream>>>(toks, emb, e_bf);
  gemm_bf<0><<<384, 256, 0, stream>>>(e_bf, wihD_bf, dec_bih, gi_e, nullptr,
                                      16, 1024, 1024, 1024, 3072, 0);
  // decoder scan (persistent)
  k_dec_scan<<<128, 256, 0, stream>>>(gi_e, dec_whh, dec_wih, dec_bhh, keys_bf,
                                      enc_bf, hcat, hfp, hbf, cnt);

  // batched output projection in two N-halves (outW_bf aliases dead buffers)
  k_conv<<<2048, 256, 0, stream>>>(out_W, outW_bf, 4096000);
  gemm_bf<2><<<2000, 256, 0, stream>>>(hcat, outW_bf, out_b, out, nullptr,
                                       16, 2048, 2048, 2048, 0, 0);
  k_conv<<<2048, 256, 0, stream>>>(out_W + (size_t)16000 * 2048, outW_bf, 4096000);
  gemm_bf<2><<<2000, 256, 0, stream>>>(hcat, outW_bf, out_b + 16000, out, nullptr,
                                       16, 2048, 2048, 2048, 0, 16000);
  // out[:, 0, :] one-hot
  k_onehot<<<4000, 256, 0, stream>>>(toks, out);
}

// Round 3
// 3375.060 us; speedup vs baseline: 2.6021x; 1.2952x over previous
//
#include <hip/hip_runtime.h>

typedef float f32x4 __attribute__((ext_vector_type(4)));
typedef __bf16 bf16x8 __attribute__((ext_vector_type(8)));

#define DI static __device__ __forceinline__

DI unsigned short f2bf(float f) {
  unsigned u = __float_as_uint(f);
  u = (u + 0x7fffu + ((u >> 16) & 1u)) >> 16;
  return (unsigned short)u;
}
DI unsigned pk2(float lo, float hi) {
  return (unsigned)f2bf(lo) | ((unsigned)f2bf(hi) << 16);
}
DI float bflo(unsigned u) { return __uint_as_float(u << 16); }
DI float bfhi(unsigned u) { return __uint_as_float(u & 0xffff0000u); }
DI float sigm(float x) { return 1.0f / (1.0f + expf(-x)); }

DI void gl_lds16(const unsigned short* g, unsigned short* l) {
  __builtin_amdgcn_global_load_lds(
      (const __attribute__((address_space(1))) unsigned int*)g,
      (__attribute__((address_space(3))) unsigned int*)l, 16, 0, 0);
}

// --- device-coherent (sc1) access helpers: data visible at L3 across XCDs ---
DI void st32_sc1(unsigned* p, unsigned v) {
  __hip_atomic_store(p, v, __ATOMIC_RELAXED, __HIP_MEMORY_SCOPE_AGENT);
}
DI void st64_sc1(unsigned long long* p, unsigned long long v) {
  __hip_atomic_store(p, v, __ATOMIC_RELAXED, __HIP_MEMORY_SCOPE_AGENT);
}
DI bf16x8 ld16_sc1(const unsigned short* p) {
  unsigned long long lo = __hip_atomic_load((const unsigned long long*)p,
                                            __ATOMIC_RELAXED, __HIP_MEMORY_SCOPE_AGENT);
  unsigned long long hi = __hip_atomic_load((const unsigned long long*)(p + 4),
                                            __ATOMIC_RELAXED, __HIP_MEMORY_SCOPE_AGENT);
  union { unsigned long long q[2]; bf16x8 v; } u;
  u.q[0] = lo; u.q[1] = hi;
  return u.v;
}

// fence-free grid barrier: cross-block data travels via sc1 ops, so the only
// requirement is each wave's vmcnt drain (done by __syncthreads) before the
// relaxed agent-scope flag add. No wbl2/inv.
DI void gridbar(int* c, int nblk) {
  __syncthreads();
  if (threadIdx.x == 0) {
    __hip_atomic_fetch_add(c, 1, __ATOMIC_RELAXED, __HIP_MEMORY_SCOPE_AGENT);
    while (__hip_atomic_load(c, __ATOMIC_RELAXED, __HIP_MEMORY_SCOPE_AGENT) < nblk)
      __builtin_amdgcn_s_sleep(1);
  }
  __syncthreads();
}

// ---------------------------------------------------------------------------
// Fold tiny per-feature projections + fi into M[1024][16], b0[1024]
// ---------------------------------------------------------------------------
__global__ void k_fold(const float* __restrict__ tW, const float* __restrict__ tb,
                       const float* __restrict__ hW, const float* __restrict__ hb,
                       const float* __restrict__ cW, const float* __restrict__ cb,
                       const float* __restrict__ tiW, const float* __restrict__ tib,
                       const float* __restrict__ oW, const float* __restrict__ ob,
                       const float* __restrict__ fiW, const float* __restrict__ fib,
                       float* __restrict__ M, float* __restrict__ b0v)
{
  int g = blockIdx.x * 256 + threadIdx.x;
  if (g >= 1024 * 17) return;
  int h = g / 17, f = g - h * 17;
  const float* fw = fiW + (size_t)h * 2048;
  float s = 0.f;
  if (f == 16) {
    for (int k = 0; k < 256; ++k) s += fw[k] * tb[k];
    for (int k = 0; k < 256; ++k) s += fw[256 + k] * hb[k];
    for (int k = 0; k < 256; ++k) s += fw[512 + k] * cb[k];
    for (int k = 0; k < 256; ++k) s += fw[768 + k] * tib[k];
    for (int r = 0; r < 1024; ++r) s += fw[1024 + r] * ob[r];
    b0v[h] = s + fib[h];
  } else if (f == 0) {
    for (int k = 0; k < 256; ++k) s += fw[k] * tW[k];
    M[h * 16 + 0] = s;
  } else if (f == 1) {
    for (int k = 0; k < 256; ++k) s += fw[256 + k] * hW[k];
    M[h * 16 + 1] = s;
  } else if (f == 2) {
    for (int k = 0; k < 256; ++k) s += fw[512 + k] * cW[k];
    M[h * 16 + 2] = s;
  } else if (f == 11) {
    for (int k = 0; k < 256; ++k) s += fw[768 + k] * tiW[2 * k];
    M[h * 16 + 11] = s;
  } else if (f == 12) {
    for (int k = 0; k < 256; ++k) s += fw[768 + k] * tiW[2 * k + 1];
    M[h * 16 + 12] = s;
  } else {
    int col = (f <= 10) ? (f - 3) : (f - 5);
    for (int r = 0; r < 1024; ++r) s += fw[1024 + r] * oW[r * 11 + col];
    M[h * 16 + f] = s;
  }
}

__global__ __launch_bounds__(256)
void k_proj(const float* __restrict__ feat, const float* __restrict__ M,
            const float* __restrict__ b0v, unsigned short* __restrict__ proj)
{
  __shared__ float ft[16];
  int bs = blockIdx.x;
  int h = blockIdx.y * 256 + threadIdx.x;
  if (threadIdx.x < 16) ft[threadIdx.x] = feat[bs * 16 + threadIdx.x];
  __syncthreads();
  float sum = b0v[h];
  const float* mr = M + h * 16;
#pragma unroll
  for (int f = 0; f < 16; ++f) sum += mr[f] * ft[f];
  proj[(size_t)bs * 1024 + h] = f2bf(tanhf(sum));
}

// ---------------------------------------------------------------------------
// fp32 -> bf16 converters
// ---------------------------------------------------------------------------
__global__ void k_conv(const float* __restrict__ s, unsigned short* __restrict__ d, int n8)
{
  for (long i = (long)blockIdx.x * 256 + threadIdx.x; i < n8; i += (long)gridDim.x * 256) {
    const float* p = s + i * 8;
    f32x4 a = *(const f32x4*)p, b = *(const f32x4*)(p + 4);
    uint4 o;
    o.x = pk2(a[0], a[1]); o.y = pk2(a[2], a[3]);
    o.z = pk2(b[0], b[1]); o.w = pk2(b[2], b[3]);
    *(uint4*)(d + i * 8) = o;
  }
}

// rows x 1024 from a ld-2048 matrix (col offset 0)
__global__ void k_conv_str(const float* __restrict__ s, unsigned short* __restrict__ d)
{
  int r = blockIdx.x;
  int c = threadIdx.x * 4;
  f32x4 a = *(const f32x4*)(s + (size_t)r * 2048 + c);
  uint2 o; o.x = pk2(a[0], a[1]); o.y = pk2(a[2], a[3]);
  *(uint2*)(d + (size_t)r * 1024 + c) = o;
}

__global__ void k_gather_e(const int* __restrict__ toks, const float* __restrict__ emb,
                           unsigned short* __restrict__ e_bf)
{
  int row = blockIdx.x;               // 2048
  int t = row >> 5, b = row & 31;
  unsigned short* dst = e_bf + (size_t)row * 1024 + threadIdx.x * 4;
  if (t < 63) {
    int tok = toks[b * 64 + t];
    f32x4 a = *(const f32x4*)(emb + (size_t)tok * 1024 + threadIdx.x * 4);
    uint2 o; o.x = pk2(a[0], a[1]); o.y = pk2(a[2], a[3]);
    *(uint2*)dst = o;
  } else {
    uint2 o; o.x = 0u; o.y = 0u;
    *(uint2*)dst = o;
  }
}

__global__ void k_onehot(const int* __restrict__ toks, float* __restrict__ out)
{
  int i = blockIdx.x * 256 + threadIdx.x;
  if (i >= 32 * 32000) return;
  int b = i / 32000, v = i - b * 32000;
  out[(size_t)b * 64 * 32000 + v] = (v == toks[0]) ? 1.0f : 0.0f;
}

// ---------------------------------------------------------------------------
// bf16 MFMA GEMM, m97 structure: C[M,N] = A[M,K] * B[N,K]^T + bias[N]
// ---------------------------------------------------------------------------
template<int MODE>
__global__ __launch_bounds__(256)
void gemm_bf(const unsigned short* __restrict__ A, const unsigned short* __restrict__ B,
             const float* __restrict__ bias, float* __restrict__ Cf,
             unsigned short* __restrict__ Cb,
             int tiles_m, int K, int lda, int ldb, int ldc, int coloff)
{
  __shared__ unsigned short As[4096];
  __shared__ unsigned short Bs[4096];
  const int nblk = gridDim.x;
  const int cpx = nblk >> 3;
  const int bid = blockIdx.x;
  const int id = (bid & 7) * cpx + (bid >> 3);     // XCD-contiguous work ids
  const int tm = id % tiles_m, tn = id / tiles_m;
  const int tid = threadIdx.x;
  const int lane = tid & 63, wave = tid >> 6;
  const int wm = (wave & 1) << 6, wn = (wave >> 1) << 6;
  const int r0 = tid >> 2, kc0 = (tid & 3) << 3;
  const unsigned short* ga0 = A + (size_t)(tm * 128 + r0) * lda + kc0;
  const unsigned short* ga1 = A + (size_t)(tm * 128 + 64 + r0) * lda + kc0;
  const unsigned short* gb0 = B + (size_t)(tn * 128 + r0) * ldb + kc0;
  const unsigned short* gb1 = B + (size_t)(tn * 128 + 64 + r0) * ldb + kc0;
  const int lr = lane & 15, lkb = (lane >> 4) << 3;

  f32x4 acc[4][4];
#pragma unroll
  for (int m = 0; m < 4; ++m)
#pragma unroll
    for (int n = 0; n < 4; ++n) { acc[m][n][0]=0.f; acc[m][n][1]=0.f; acc[m][n][2]=0.f; acc[m][n][3]=0.f; }

  for (int kt = 0; kt < K; kt += 32) {
    __syncthreads();
    gl_lds16(ga0 + kt, &As[tid * 8]);
    gl_lds16(ga1 + kt, &As[(tid + 256) * 8]);
    gl_lds16(gb0 + kt, &Bs[tid * 8]);
    gl_lds16(gb1 + kt, &Bs[(tid + 256) * 8]);
    __syncthreads();
    bf16x8 af[4], bfv[4];
#pragma unroll
    for (int m = 0; m < 4; ++m) af[m] = *(const bf16x8*)&As[(wm + m * 16 + lr) * 32 + lkb];
#pragma unroll
    for (int n = 0; n < 4; ++n) bfv[n] = *(const bf16x8*)&Bs[(wn + n * 16 + lr) * 32 + lkb];
#pragma unroll
    for (int m = 0; m < 4; ++m)
#pragma unroll
      for (int n = 0; n < 4; ++n)
        acc[m][n] = __builtin_amdgcn_mfma_f32_16x16x32_bf16(af[m], bfv[n], acc[m][n], 0, 0, 0);
  }

#pragma unroll
  for (int m = 0; m < 4; ++m) {
    int rb = tm * 128 + wm + m * 16 + ((lane >> 4) << 2);
#pragma unroll
    for (int n = 0; n < 4; ++n) {
      int c = tn * 128 + wn + n * 16 + lr;
      float bb = bias[c];
#pragma unroll
      for (int i = 0; i < 4; ++i) {
        float v = acc[m][n][i] + bb;
        int r = rb + i;
        if (MODE == 0) {
          Cf[(size_t)r * ldc + c] = v;
        } else if (MODE == 1) {
          Cb[(size_t)r * ldc + c] = f2bf(v);
        } else {
          if (r < 2016) {
            int t = r >> 5, b2 = r & 31;
            Cf[((size_t)b2 * 64 + t + 1) * 32000 + coloff + c] = v;
          }
        }
      }
    }
  }
}

// ---------------------------------------------------------------------------
// Persistent encoder scan. 64 blocks x 256. Cross-block h (bf16) via sc1
// stores/loads (hbf is double-buffered -> addresses reused -> must bypass L2).
// fp32 h state carried in registers per gate thread.
// ---------------------------------------------------------------------------
__global__ __launch_bounds__(256, 1)
void k_enc_scan(const float* __restrict__ gi_all, const float* __restrict__ whh,
                const float* __restrict__ bhh, unsigned short* __restrict__ hbf,
                float* __restrict__ hfp, unsigned short* __restrict__ enc_bf,
                int* __restrict__ cnt)
{
  __shared__ unsigned short W[48 * 1024];
  __shared__ float Cred[4 * 2 * 3 * 64 * 4];
  const int tid = threadIdx.x;
  const int lane = tid & 63, wave = tid >> 6;
  const int j0 = blockIdx.x * 16;

  // stage 48 weight rows (r16,z16,n16) into LDS as bf16, XOR-swizzled chunks
  for (int i = tid; i < 48 * 128; i += 256) {
    int r = i >> 7, c = i & 127;
    int gr = ((r >> 4) << 10) + j0 + (r & 15);
    const float* src = whh + ((size_t)gr << 10) + (c << 3);
    f32x4 a = *(const f32x4*)src, b = *(const f32x4*)(src + 4);
    uint4 o;
    o.x = pk2(a[0], a[1]); o.y = pk2(a[2], a[3]);
    o.z = pk2(b[0], b[1]); o.w = pk2(b[2], b[3]);
    *(uint4*)&W[(r << 10) + ((c ^ (r & 7)) << 3)] = o;
  }
  __syncthreads();

  // per-thread gate cell decomposition (2 cells)
  int cb[2], cj[2], clb[2], creg[2], cm[2];
  float bh0[2], bh1[2], bh2[2];
  float hp[2] = {0.f, 0.f};          // fp32 h state lives in registers
#pragma unroll
  for (int cc = 0; cc < 2; ++cc) {
    int cell = tid + (cc << 8);
    cb[cc] = cell >> 4; cj[cc] = cell & 15;
    clb[cc] = ((cb[cc] & 15) >> 2) * 16;
    creg[cc] = cb[cc] & 3; cm[cc] = cb[cc] >> 4;
    bh0[cc] = bhh[j0 + cj[cc]];
    bh1[cc] = bhh[1024 + j0 + cj[cc]];
    bh2[cc] = bhh[2048 + j0 + cj[cc]];
  }

#pragma unroll 1
  for (int s = 0; s < 128; ++s) {
    const int rb = s & 1, wb = rb ^ 1;
    const unsigned short* hr = hbf + rb * 32768;

    // prefetch gi for gate phase (read-only, normal loads)
    float gp[2][3];
#pragma unroll
    for (int cc = 0; cc < 2; ++cc) {
      const float* gi = gi_all + ((size_t)cb[cc] * 128 + s) * 3072 + j0 + cj[cc];
      gp[cc][0] = gi[0]; gp[cc][1] = gi[1024]; gp[cc][2] = gi[2048];
    }

    // MFMA phase, wave handles k range [wave*256, wave*256+256)
    const int k0 = wave << 8;
    bf16x8 af[2][8];
#pragma unroll
    for (int kk = 0; kk < 8; ++kk) {
      int k = k0 + kk * 32 + ((lane >> 4) << 3);
      af[0][kk] = ld16_sc1(hr + (size_t)(lane & 15) * 1024 + k);
      af[1][kk] = ld16_sc1(hr + (size_t)(16 + (lane & 15)) * 1024 + k);
    }
    f32x4 acc[2][3];
#pragma unroll
    for (int m = 0; m < 2; ++m)
#pragma unroll
      for (int n = 0; n < 3; ++n) { acc[m][n][0]=0.f; acc[m][n][1]=0.f; acc[m][n][2]=0.f; acc[m][n][3]=0.f; }
#pragma unroll
    for (int kk = 0; kk < 8; ++kk) {
      int c = ((k0 + kk * 32) >> 3) + (lane >> 4);
#pragma unroll
      for (int n = 0; n < 3; ++n) {
        int wr = n * 16 + (lane & 15);
        bf16x8 bfr = *(const bf16x8*)&W[(wr << 10) + ((c ^ (wr & 7)) << 3)];
        acc[0][n] = __builtin_amdgcn_mfma_f32_16x16x32_bf16(af[0][kk], bfr, acc[0][n], 0, 0, 0);
        acc[1][n] = __builtin_amdgcn_mfma_f32_16x16x32_bf16(af[1][kk], bfr, acc[1][n], 0, 0, 0);
      }
    }
#pragma unroll
    for (int m = 0; m < 2; ++m)
#pragma unroll
      for (int n = 0; n < 3; ++n)
        *(f32x4*)&Cred[((((wave * 2 + m) * 3 + n) * 64) + lane) << 2] = acc[m][n];
    __syncthreads();

    // gate phase: 2 cells/thread
    float h2v[2];
#pragma unroll
    for (int cc = 0; cc < 2; ++cc) {
      int lj = clb[cc] + cj[cc], reg = creg[cc], m = cm[cc];
      float Cr = 0.f, Cz = 0.f, Cn = 0.f;
#pragma unroll
      for (int w = 0; w < 4; ++w) {
        Cr += Cred[((((w * 2 + m) * 3 + 0) * 64 + lj) << 2) + reg];
        Cz += Cred[((((w * 2 + m) * 3 + 1) * 64 + lj) << 2) + reg];
        Cn += Cred[((((w * 2 + m) * 3 + 2) * 64 + lj) << 2) + reg];
      }
      float r = sigm(gp[cc][0] + Cr + bh0[cc]);
      float z = sigm(gp[cc][1] + Cz + bh1[cc]);
      float n = tanhf(gp[cc][2] + r * (Cn + bh2[cc]));
      float h2 = (1.f - z) * n + z * hp[cc];
      h2v[cc] = h2; hp[cc] = h2;
    }
    // fp32 state export (only final step consumed, by decoder; normal stores)
    hfp[wb * 32768 + cb[0] * 1024 + j0 + cj[0]] = h2v[0];
    hfp[wb * 32768 + cb[1] * 1024 + j0 + cj[1]] = h2v[1];
    // packed bf16 writes: pair adjacent j via shfl, even lanes store 4B
    unsigned short s0 = f2bf(h2v[0]), s1 = f2bf(h2v[1]);
    unsigned o0 = (unsigned)__shfl_xor((int)(unsigned)s0, 1);
    unsigned o1 = (unsigned)__shfl_xor((int)(unsigned)s1, 1);
    if ((tid & 1) == 0) {
      int j = cj[0];                    // even
      unsigned p0 = (unsigned)s0 | (o0 << 16);
      unsigned p1 = (unsigned)s1 | (o1 << 16);
      st32_sc1((unsigned*)&hbf[wb * 32768 + cb[0] * 1024 + j0 + j], p0);
      st32_sc1((unsigned*)&hbf[wb * 32768 + cb[1] * 1024 + j0 + j], p1);
      *(unsigned*)&enc_bf[((size_t)cb[0] * 128 + s) * 1024 + j0 + j] = p0;
      *(unsigned*)&enc_bf[((size_t)cb[1] * 128 + s) * 1024 + j0 + j] = p1;
    }
    gridbar(&cnt[s], 64);
  }
}

// ---------------------------------------------------------------------------
// Persistent decoder scan. 128 blocks x 256. hcat rows are single-assignment:
// sc1 stores (publish to L3), normal first-touch loads are safe + L2-cacheable.
// fp32 h state in registers.
// ---------------------------------------------------------------------------
__global__ __launch_bounds__(256, 1)
void k_dec_scan(const float* __restrict__ gi_e, const float* __restrict__ whh,
                const float* __restrict__ wih, const float* __restrict__ bhh,
                const unsigned short* __restrict__ keys,
                const unsigned short* __restrict__ enc_bf,
                unsigned short* __restrict__ hcat, const float* __restrict__ hfp0,
                const unsigned short* __restrict__ hbf0, int* __restrict__ cnt)
{
  __shared__ unsigned short Wh[32 * 1024];
  __shared__ unsigned short Wx[32 * 1024];
  __shared__ float Cred[4 * 2 * 2 * 64 * 4];
  __shared__ unsigned short hsh[1024];
  __shared__ float sarr[128];
  __shared__ float earr[128];
  const int tid = threadIdx.x;
  const int lane = tid & 63, wave = tid >> 6;
  const int blk = blockIdx.x;
  const int j0 = blk * 8;

  // stage weights: rows 0-7 r, 8-15 z, 16-23 n, 24-31 zero
  for (int i = tid; i < 32 * 128; i += 256) {
    int r = i >> 7, c = i & 127;
    int off = (r << 10) + ((c ^ (r & 7)) << 3);
    uint4 oh, ox;
    oh.x = oh.y = oh.z = oh.w = 0u; ox = oh;
    if (r < 24) {
      int gr = ((r >> 3) << 10) + j0 + (r & 7);
      const float* sh = whh + ((size_t)gr << 10) + (c << 3);
      f32x4 a = *(const f32x4*)sh, b = *(const f32x4*)(sh + 4);
      oh.x = pk2(a[0], a[1]); oh.y = pk2(a[2], a[3]);
      oh.z = pk2(b[0], b[1]); oh.w = pk2(b[2], b[3]);
      const float* sx = wih + ((size_t)gr << 11) + 1024 + (c << 3);
      f32x4 e = *(const f32x4*)sx, f = *(const f32x4*)(sx + 4);
      ox.x = pk2(e[0], e[1]); ox.y = pk2(e[2], e[3]);
      ox.z = pk2(f[0], f[1]); ox.w = pk2(f[2], f[3]);
    }
    *(uint4*)&Wh[off] = oh;
    *(uint4*)&Wx[off] = ox;
  }
  __syncthreads();

  // gate cell decomposition (1 cell/thread)
  const int gb = tid >> 3, gj = tid & 7;
  const int glb = ((gb & 15) >> 2) * 16;
  const int greg = gb & 3, gm = gb >> 4;
  const float bh0 = bhh[j0 + gj];
  const float bh1 = bhh[1024 + j0 + gj];
  const float bh2 = bhh[2048 + j0 + gj];
  float hpv = hfp0[gb * 1024 + j0 + gj];   // fp32 h state in register

#pragma unroll 1
  for (int t = 0; t < 63; ++t) {
    // ---------------- attention (blocks 0..31: one per batch) -------------
    if (blk < 32) {
      const int b = blk;
      const unsigned short* hsrc = (t == 0) ? (hbf0 + b * 1024)
                                            : (hcat + ((size_t)(t - 1) * 32 + b) * 2048);
      *(uint2*)&hsh[tid * 4] = *(const uint2*)(hsrc + tid * 4);
      __syncthreads();
      {
        int sp = tid >> 1, kh = (tid & 1) << 9;
        const unsigned short* kr = keys + ((size_t)b * 128 + sp) * 1024 + kh;
        float a = 0.f;
#pragma unroll 8
        for (int c = 0; c < 512; c += 8) {
          uint4 kv = *(const uint4*)(kr + c);
          uint4 hv = *(const uint4*)&hsh[kh + c];
          a += bflo(kv.x) * bflo(hv.x) + bfhi(kv.x) * bfhi(hv.x)
             + bflo(kv.y) * bflo(hv.y) + bfhi(kv.y) * bfhi(hv.y)
             + bflo(kv.z) * bflo(hv.z) + bfhi(kv.z) * bfhi(hv.z)
             + bflo(kv.w) * bflo(hv.w) + bfhi(kv.w) * bfhi(hv.w);
        }
        a += __shfl_xor(a, 1);
        if ((tid & 1) == 0) sarr[sp] = a * 0.03125f;
      }
      __syncthreads();
      float mx = -1e30f;
#pragma unroll 16
      for (int i2 = 0; i2 < 128; ++i2) mx = fmaxf(mx, sarr[i2]);
      if (tid < 128) earr[tid] = expf(sarr[tid] - mx);
      __syncthreads();
      float sum = 0.f;
#pragma unroll 16
      for (int i2 = 0; i2 < 128; ++i2) sum += earr[i2];
      float winv = 1.f / sum;
      f32x4 cacc; cacc[0]=0.f; cacc[1]=0.f; cacc[2]=0.f; cacc[3]=0.f;
      const unsigned short* eb = enc_bf + ((size_t)b << 17) + tid * 4;
#pragma unroll 4
      for (int s2 = 0; s2 < 128; ++s2) {
        float w = earr[s2] * winv;
        uint2 ev = *(const uint2*)(eb + ((size_t)s2 << 10));
        cacc[0] += w * bflo(ev.x); cacc[1] += w * bfhi(ev.x);
        cacc[2] += w * bflo(ev.y); cacc[3] += w * bfhi(ev.y);
      }
      unsigned long long cw = (unsigned long long)pk2(cacc[0], cacc[1])
                            | ((unsigned long long)pk2(cacc[2], cacc[3]) << 32);
      st64_sc1((unsigned long long*)(hcat + ((size_t)t * 32 + b) * 2048 + 1024 + tid * 4), cw);
    }
    gridbar(&cnt[128 + t * 2], 128);

    // ---------------- GRU phase ------------------------------------------
    const float* gie = gi_e + ((size_t)t * 32 + gb) * 3072 + j0 + gj;
    float g0 = gie[0], g1 = gie[1024], g2 = gie[2048];

    const int part = wave >> 1;
    const int kh2 = (wave & 1) << 9;
    const unsigned short* abase;
    size_t astr;
    if (part == 0) {
      if (t == 0) { abase = hbf0; astr = 1024; }
      else { abase = hcat + (size_t)(t - 1) * 32 * 2048; astr = 2048; }
    } else {
      abase = hcat + (size_t)t * 32 * 2048 + 1024; astr = 2048;
    }
    const unsigned short* Wl = part ? Wx : Wh;
    f32x4 acc[2][2];
#pragma unroll
    for (int m = 0; m < 2; ++m)
#pragma unroll
      for (int n = 0; n < 2; ++n) { acc[m][n][0]=0.f; acc[m][n][1]=0.f; acc[m][n][2]=0.f; acc[m][n][3]=0.f; }
#pragma unroll
    for (int hh = 0; hh < 2; ++hh) {
      bf16x8 af[2][8];
#pragma unroll
      for (int kk = 0; kk < 8; ++kk) {
        int k = kh2 + hh * 256 + kk * 32 + ((lane >> 4) << 3);
        af[0][kk] = *(const bf16x8*)(abase + (size_t)(lane & 15) * astr + k);
        af[1][kk] = *(const bf16x8*)(abase + (size_t)(16 + (lane & 15)) * astr + k);
      }
#pragma unroll
      for (int kk = 0; kk < 8; ++kk) {
        int c = ((kh2 + hh * 256 + kk * 32) >> 3) + (lane >> 4);
#pragma unroll
        for (int n = 0; n < 2; ++n) {
          int wr = n * 16 + (lane & 15);
          bf16x8 bfr = *(const bf16x8*)&Wl[(wr << 10) + ((c ^ (wr & 7)) << 3)];
          acc[0][n] = __builtin_amdgcn_mfma_f32_16x16x32_bf16(af[0][kk], bfr, acc[0][n], 0, 0, 0);
          acc[1][n] = __builtin_amdgcn_mfma_f32_16x16x32_bf16(af[1][kk], bfr, acc[1][n], 0, 0, 0);
        }
      }
    }
#pragma unroll
    for (int m = 0; m < 2; ++m)
#pragma unroll
      for (int n = 0; n < 2; ++n)
        *(f32x4*)&Cred[((((wave * 2 + m) * 2 + n) * 64) + lane) << 2] = acc[m][n];
    __syncthreads();

    // gates: 1 cell/thread
    {
      float Chr = 0.f, Chz = 0.f, Chn = 0.f, Cxr = 0.f, Cxz = 0.f, Cxn = 0.f;
#pragma unroll
      for (int w = 0; w < 2; ++w) {
        Chr += Cred[((((w * 2 + gm) * 2 + 0) * 64 + glb + gj) << 2) + greg];
        Chz += Cred[((((w * 2 + gm) * 2 + 0) * 64 + glb + gj + 8) << 2) + greg];
        Chn += Cred[((((w * 2 + gm) * 2 + 1) * 64 + glb + gj) << 2) + greg];
        Cxr += Cred[(((((w + 2) * 2 + gm) * 2 + 0) * 64 + glb + gj) << 2) + greg];
        Cxz += Cred[(((((w + 2) * 2 + gm) * 2 + 0) * 64 + glb + gj + 8) << 2) + greg];
        Cxn += Cred[(((((w + 2) * 2 + gm) * 2 + 1) * 64 + glb + gj) << 2) + greg];
      }
      float r = sigm(g0 + Cxr + Chr + bh0);
      float z = sigm(g1 + Cxz + Chz + bh1);
      float n2 = tanhf(g2 + Cxn + r * (Chn + bh2));
      float h2 = (1.f - z) * n2 + z * hpv;
      hpv = h2;
      unsigned short sv = f2bf(h2);
      unsigned ov = (unsigned)__shfl_xor((int)(unsigned)sv, 1);
      if ((tid & 1) == 0) {
        unsigned pv = (unsigned)sv | (ov << 16);
        st32_sc1((unsigned*)&hcat[((size_t)t * 32 + gb) * 2048 + j0 + gj], pv);
      }
    }
    gridbar(&cnt[128 + t * 2 + 1], 128);
  }
}

// ---------------------------------------------------------------------------
extern "C" void kernel_launch(void* const* d_in, const int* in_sizes, int n_in,
                              void* d_out, int out_size, void* d_ws, size_t ws_size,
                              hipStream_t stream)
{
  const float* features = (const float*)d_in[0];
  const int*   toks     = (const int*)d_in[1];
  const float* temp_W = (const float*)d_in[2];  const float* temp_b = (const float*)d_in[3];
  const float* hum_W  = (const float*)d_in[4];  const float* hum_b  = (const float*)d_in[5];
  const float* cloud_W= (const float*)d_in[6];  const float* cloud_b= (const float*)d_in[7];
  const float* time_W = (const float*)d_in[8];  const float* time_b = (const float*)d_in[9];
  const float* other_W= (const float*)d_in[10]; const float* other_b= (const float*)d_in[11];
  const float* fi_W   = (const float*)d_in[12]; const float* fi_b   = (const float*)d_in[13];
  const float* enc_wih= (const float*)d_in[14]; const float* enc_whh= (const float*)d_in[15];
  const float* enc_bih= (const float*)d_in[16]; const float* enc_bhh= (const float*)d_in[17];
  const float* emb    = (const float*)d_in[18];
  const float* attn_W = (const float*)d_in[19]; const float* attn_b = (const float*)d_in[20];
  const float* dec_wih= (const float*)d_in[21]; const float* dec_whh= (const float*)d_in[22];
  const float* dec_bih= (const float*)d_in[23]; const float* dec_bhh= (const float*)d_in[24];
  const float* out_W  = (const float*)d_in[25]; const float* out_b  = (const float*)d_in[26];
  float* out = (float*)d_out;
  char* ws = (char*)d_ws;

  int*            cnt     = (int*)(ws + 0);                        // 4 KB
  float*          Mf      = (float*)(ws + 4096);                   // 64 KB
  float*          b0v     = (float*)(ws + 69632);                  // 4 KB
  float*          hfp     = (float*)(ws + 73728);                  // 256 KB
  unsigned short* hbf     = (unsigned short*)(ws + 335872);        // 128 KB
  unsigned short* hcat    = (unsigned short*)(ws + 466944);        // 8 MB  [2048][2048]
  unsigned short* keys_bf = (unsigned short*)(ws + 8855552);       // 8 MB
  unsigned short* enc_bf  = (unsigned short*)(ws + 17244160);      // 8 MB
  float*          gi_e    = (float*)(ws + 25632768);               // 24 MB
  float*          gi_all  = (float*)(ws + 50798592);               // 48 MB
  unsigned short* proj_bf = (unsigned short*)(ws + 101130240);     // 8 MB
  unsigned short* e_bf    = (unsigned short*)(ws + 109518848);     // 4 MB
  unsigned short* wihE_bf = (unsigned short*)(ws + 113713152);     // 6 MB
  unsigned short* attnW_bf= (unsigned short*)(ws + 120004608);     // 2 MB
  unsigned short* wihD_bf = (unsigned short*)(ws + 122101760);     // 6 MB
  // out_W bf16 halves alias the (dead-by-then) gi_e/gi_all region
  unsigned short* outW_bf = (unsigned short*)(ws + 25632768);      // 62.5 MB

  // zero barrier counters, h state, hcat padding rows (2016..2047)
  hipMemsetAsync(ws, 0, 4096, stream);
  hipMemsetAsync(ws + 73728, 0, 262144 + 131072, stream);
  hipMemsetAsync(ws + 466944 + (size_t)2016 * 2048 * 2, 0, 32 * 2048 * 2, stream);

  // weight conversions
  k_conv<<<1536, 256, 0, stream>>>(enc_wih, wihE_bf, 393216);
  k_conv<<<512, 256, 0, stream>>>(attn_W, attnW_bf, 131072);
  k_conv_str<<<3072, 256, 0, stream>>>(dec_wih, wihD_bf);

  // feature pipeline
  k_fold<<<68, 256, 0, stream>>>(temp_W, temp_b, hum_W, hum_b, cloud_W, cloud_b,
                                 time_W, time_b, other_W, other_b, fi_W, fi_b, Mf, b0v);
  k_proj<<<dim3(4096, 4), 256, 0, stream>>>(features, Mf, b0v, proj_bf);

  // encoder input gates (batched): gi_all[4096,3072]
  gemm_bf<0><<<768, 256, 0, stream>>>(proj_bf, wihE_bf, enc_bih, gi_all, nullptr,
                                      32, 1024, 1024, 1024, 3072, 0);
  // encoder scan (persistent)
  k_enc_scan<<<64, 256, 0, stream>>>(gi_all, enc_whh, enc_bhh, hbf, hfp, enc_bf, cnt);

  // attention keys (bf16 out)
  gemm_bf<1><<<256, 256, 0, stream>>>(enc_bf, attnW_bf, attn_b, nullptr, keys_bf,
                                      32, 1024, 1024, 1024, 1024, 0);
  // decoder embedding-path gates
  k_gather_e<<<2048, 256, 0, stream>>>(toks, emb, e_bf);
  gemm_bf<0><<<384, 256, 0, stream>>>(e_bf, wihD_bf, dec_bih, gi_e, nullptr,
                                      16, 1024, 1024, 1024, 3072, 0);
  // decoder scan (persistent)
  k_dec_scan<<<128, 256, 0, stream>>>(gi_e, dec_whh, dec_wih, dec_bhh, keys_bf,
                                      enc_bf, hcat, hfp, hbf, cnt);

  // batched output projection in two N-halves (outW_bf aliases dead buffers)
  k_conv<<<2048, 256, 0, stream>>>(out_W, outW_bf, 4096000);
  gemm_bf<2><<<2000, 256, 0, stream>>>(hcat, outW_bf, out_b, out, nullptr,
                                       16, 2048, 2048, 2048, 0, 0);
  k_conv<<<2048, 256, 0, stream>>>(out_W + (size_t)16000 * 2048, outW_bf, 4096000);
  gemm_bf<2><<<2000, 256, 0, stream>>>(hcat, outW_bf, out_b + 16000, out, nullptr,
                                       16, 2048, 2048, 2048, 0, 16000);
  // out[:, 0, :] one-hot
  k_onehot<<<4000, 256, 0, stream>>>(toks, out);
}